// Round 5
// baseline (173.877 us; speedup 1.0000x reference)
//
#include <hip/hip_runtime.h>
#include <hip/hip_cooperative_groups.h>

namespace cg = cooperative_groups;

// Problem constants
#define SOM_DIM 512
#define SOM_ROWS 65536          // 256*256
#define SOM_ELEMS (SOM_ROWS * SOM_DIM)

// Fused cooperative kernel geometry
#define FGRID 512               // 2 blocks/CU * 256 CUs
#define FWAVES 4                // 256 threads
#define FROWS_PER_WAVE 32       // 512*4*32 = 65536 rows
#define FLDS_ROWS 9             // rows per wave staged in LDS
#define FREG_ROWS 23            // rows per wave staged in registers
#define FDYN_LDS (FWAVES * FLDS_ROWS * SOM_DIM * 4)  // 73728 B -> 2 blocks/CU

typedef float f32x4 __attribute__((ext_vector_type(4)));
typedef float f32x2 __attribute__((ext_vector_type(2)));

// ================= Fused persistent kernel =================
// Phase A: read weights ONCE, compute distances, stash rows in LDS+VGPRs.
// grid.sync. Phase B: update from on-chip copy, write output. HBM traffic
// = 128 MB read + 128 MB write (no re-read).
__global__ __launch_bounds__(256, 2) void som_fused(
    const float* __restrict__ w, const float* __restrict__ in,
    const int* __restrict__ epoch_p,
    unsigned long long* __restrict__ part,   // [FGRID*FWAVES] = [2048]
    float* __restrict__ out) {
  extern __shared__ float lds[];
  const int wave = threadIdx.x >> 6;
  const int lane = threadIdx.x & 63;
  const int row0 = blockIdx.x * (FWAVES * FROWS_PER_WAVE) + wave * FROWS_PER_WAVE;

  const f32x4* in4 = (const f32x4*)in;
  const f32x4 iv0 = in4[lane];        // floats [4*lane, 4*lane+4)
  const f32x4 iv1 = in4[lane + 64];   // floats [256+4*lane, ...)

  float* wlds = lds + wave * (FLDS_ROWS * SOM_DIM);

  float bd = 3.4e38f;
  int bi = SOM_ROWS;
  f32x4 d0[FREG_ROWS], d1[FREG_ROWS];  // statically indexed (fully unrolled)

  // ---- Phase A: distance + stash ----
#pragma unroll
  for (int r = 0; r < FROWS_PER_WAVE; ++r) {
    const f32x4* wr = (const f32x4*)(w + (size_t)(row0 + r) * SOM_DIM);
    f32x4 wv0 = wr[lane];
    f32x4 wv1 = wr[lane + 64];
    f32x4 e0 = wv0 - iv0;
    f32x4 e1 = wv1 - iv1;
    float acc = e0.x * e0.x + e0.y * e0.y + e0.z * e0.z + e0.w * e0.w +
                e1.x * e1.x + e1.y * e1.y + e1.z * e1.z + e1.w * e1.w;
#pragma unroll
    for (int off = 32; off; off >>= 1) acc += __shfl_xor(acc, off, 64);
    // rows ascend -> strict < keeps first occurrence (jnp.argmin semantics)
    if (acc < bd) { bd = acc; bi = row0 + r; }
    if (r < FLDS_ROWS) {
      f32x4* dst = (f32x4*)(wlds + r * SOM_DIM);
      dst[lane] = wv0;
      dst[lane + 64] = wv1;
    } else {
      d0[r - FLDS_ROWS] = wv0;
      d1[r - FLDS_ROWS] = wv1;
    }
  }

  if (lane == 0) {
    part[blockIdx.x * FWAVES + wave] =
        ((unsigned long long)__float_as_uint(bd) << 32) | (unsigned int)bi;
  }

  cg::this_grid().sync();

  // ---- global argmin: every wave redundantly reduces 2048 partials (L2) ----
  unsigned long long m = part[lane];
#pragma unroll
  for (int k = 1; k < 32; ++k) {
    unsigned long long v = part[lane + 64 * k];
    m = (v < m) ? v : m;
  }
#pragma unroll
  for (int off = 32; off; off >>= 1) {
    unsigned long long v = __shfl_xor(m, off, 64);
    m = (v < m) ? v : m;
  }
  const int bidx = (int)(unsigned int)(m & 0xFFFFFFFFull);
  const int br = bidx >> 8;   // N = 256
  const int bc = bidx & 255;

  if (blockIdx.x == 0 && threadIdx.x == 0) {
    out[0] = (float)br;
    out[1] = (float)bc;
  }

  // ---- Phase B: update from on-chip stash, write out ----
  const float lr = 1.0f - (float)epoch_p[0] * 0.01f;
  const float alpha_op = 0.3f * lr;
  const float sigma_op = 128.0f * lr;
  const float inv_s2 = 1.0f / (sigma_op * sigma_op);

#pragma unroll
  for (int r = 0; r < FROWS_PER_WAVE; ++r) {
    const int row = row0 + r;
    const int rr = (row >> 8) - br;
    const int cc = (row & 255) - bc;
    const float mult = alpha_op * __expf(-(float)(rr * rr + cc * cc) * inv_s2);
    f32x4 wv0, wv1;
    if (r < FLDS_ROWS) {
      const f32x4* src = (const f32x4*)(wlds + r * SOM_DIM);
      wv0 = src[lane];
      wv1 = src[lane + 64];
    } else {
      wv0 = d0[r - FLDS_ROWS];
      wv1 = d1[r - FLDS_ROWS];
    }
    f32x4 r0 = wv0 + mult * (iv0 - wv0);
    f32x4 r1 = wv1 + mult * (iv1 - wv1);
    float* ob = out + 2 + (size_t)row * SOM_DIM;  // 8B-aligned
    f32x2 a;
    a.x = r0.x; a.y = r0.y; ((f32x2*)(ob + 4 * lane))[0] = a;
    a.x = r0.z; a.y = r0.w; ((f32x2*)(ob + 4 * lane + 2))[0] = a;
    a.x = r1.x; a.y = r1.y; ((f32x2*)(ob + 256 + 4 * lane))[0] = a;
    a.x = r1.z; a.y = r1.w; ((f32x2*)(ob + 256 + 4 * lane + 2))[0] = a;
  }
}

// ================= Fallback path (R4 two-kernel) =================
#define NB 2048
__global__ __launch_bounds__(256) void som_bmu_partial(
    const float* __restrict__ w, const float* __restrict__ in,
    unsigned long long* __restrict__ part) {
  __shared__ float s_in[SOM_DIM];
  for (int i = threadIdx.x; i < SOM_DIM; i += 256) s_in[i] = in[i];
  __syncthreads();
  const int wave = threadIdx.x >> 6;
  const int lane = threadIdx.x & 63;
  const int globalWave = blockIdx.x * 4 + wave;
  const int nWaves = NB * 4;
  float bd = 3.4e38f;
  int bi = SOM_ROWS;
  const f32x4* in4 = (const f32x4*)s_in;
  for (int row = globalWave; row < SOM_ROWS; row += nWaves) {
    const f32x4* wr = (const f32x4*)(w + (size_t)row * SOM_DIM);
    float acc = 0.f;
#pragma unroll
    for (int k = 0; k < 2; ++k) {
      f32x4 wv = wr[lane + 64 * k];
      f32x4 iv = in4[lane + 64 * k];
      f32x4 d = wv - iv;
      acc += d.x * d.x + d.y * d.y + d.z * d.z + d.w * d.w;
    }
#pragma unroll
    for (int off = 32; off; off >>= 1) acc += __shfl_xor(acc, off, 64);
    if (acc < bd) { bd = acc; bi = row; }
  }
  unsigned long long pk =
      ((unsigned long long)__float_as_uint(bd) << 32) | (unsigned int)bi;
  __shared__ unsigned long long sp[4];
  if (lane == 0) sp[wave] = pk;
  __syncthreads();
  if (threadIdx.x == 0) {
    unsigned long long mm = sp[0];
#pragma unroll
    for (int k = 1; k < 4; ++k) mm = (sp[k] < mm) ? sp[k] : mm;
    part[blockIdx.x] = mm;
  }
}

__global__ __launch_bounds__(256) void som_update(
    const float* __restrict__ w, const float* __restrict__ in,
    const int* __restrict__ epoch_p,
    const unsigned long long* __restrict__ part,
    float* __restrict__ out) {
  __shared__ unsigned long long sp[256];
  unsigned long long m = ~0ull;
  for (int i = threadIdx.x; i < NB; i += 256) {
    unsigned long long v = part[i];
    m = (v < m) ? v : m;
  }
  sp[threadIdx.x] = m;
  __syncthreads();
  for (int s = 128; s; s >>= 1) {
    if ((int)threadIdx.x < s) {
      if (sp[threadIdx.x + s] < sp[threadIdx.x]) sp[threadIdx.x] = sp[threadIdx.x + s];
    }
    __syncthreads();
  }
  const int bidx = (int)(unsigned int)(sp[0] & 0xFFFFFFFFull);
  const int br = bidx >> 8;
  const int bc = bidx & 255;
  if (blockIdx.x == 0 && threadIdx.x == 0) {
    out[0] = (float)br;
    out[1] = (float)bc;
  }
  const float lr = 1.0f - (float)epoch_p[0] * 0.01f;
  const float alpha_op = 0.3f * lr;
  const float sigma_op = 128.0f * lr;
  const float inv_s2 = 1.0f / (sigma_op * sigma_op);
  const f32x2* w2 = (const f32x2*)w;
  const f32x2* in2 = (const f32x2*)in;
  f32x2* o2 = (f32x2*)(out + 2);
  const int total2 = SOM_ELEMS / 2;
  const int stride = NB * 256;
  for (int j = blockIdx.x * 256 + threadIdx.x; j < total2; j += stride) {
    const int row = j >> 8;
    const int rr = (row >> 8) - br;
    const int cc = (row & 255) - bc;
    const float mult = alpha_op * __expf(-(float)(rr * rr + cc * cc) * inv_s2);
    f32x2 wv = w2[j];
    f32x2 iv = in2[j & 255];
    o2[j] = wv + mult * (iv - wv);
  }
}

extern "C" void kernel_launch(void* const* d_in, const int* in_sizes, int n_in,
                              void* d_out, int out_size, void* d_ws, size_t ws_size,
                              hipStream_t stream) {
  const float* input_vector = (const float*)d_in[0];
  const float* weights = (const float*)d_in[1];
  const int* epoch = (const int*)d_in[2];
  float* out = (float*)d_out;
  unsigned long long* part = (unsigned long long*)d_ws;  // [2048] = 16 KB

  // allow >64KB dynamic LDS for the fused kernel (idempotent, not a stream op)
  (void)hipFuncSetAttribute((const void*)som_fused,
                            hipFuncAttributeMaxDynamicSharedMemorySize, FDYN_LDS);

  void* kargs[] = {(void*)&weights, (void*)&input_vector, (void*)&epoch,
                   (void*)&part, (void*)&out};
  hipError_t e = hipLaunchCooperativeKernel((const void*)som_fused,
                                            dim3(FGRID), dim3(256), kargs,
                                            FDYN_LDS, stream);
  if (e != hipSuccess) {
    // cooperative launch not available (e.g., under graph capture) -> 2-kernel path
    som_bmu_partial<<<NB, 256, 0, stream>>>(weights, input_vector, part);
    som_update<<<NB, 256, 0, stream>>>(weights, input_vector, epoch, part, out);
  }
}